// Round 1
// baseline (64.701 us; speedup 1.0000x reference)
//
#include <hip/hip_runtime.h>

// NbitTreeDecoder: static-shape octree decode.
// One thread per level-9 node (2^18 threads), 4 leaves per thread.
// Leaf p = 4*q + d9. Node index at level t: i_t = q >> (18-2t); digit d_t = (q >> (16-2t)) & 3.
// j_t = position of d_t-th set bit of flags[LOFF[t] + i_t]; X = sum j_t << (3*(9-t)).
// PERMUTE = reversal of 30 bits -> __brev(X) >> 2. Fields: (Xr>>{0,10,20}) & 1023.

__global__ __launch_bounds__(256) void nbit_tree_decode(
    const int* __restrict__ flags,
    const float* __restrict__ off3,
    const float* __restrict__ scl3,
    float* __restrict__ out)
{
    // level offsets (4^t - 1) / 3 for t = 0..8 (level 9 offset = 87381)
    constexpr unsigned LOFF[9] = {0u, 1u, 5u, 21u, 85u, 341u, 1365u, 5461u, 21845u};

    const unsigned q = blockIdx.x * 256u + threadIdx.x;   // level-9 node index, < 2^18

    unsigned Xp = 0u;  // 27-bit prefix (levels 0..8)
#pragma unroll
    for (int t = 0; t < 9; ++t) {
        const unsigned i = q >> (18 - 2 * t);
        const unsigned d = (q >> (16 - 2 * t)) & 3u;
        unsigned f = (unsigned)flags[LOFF[t] + i];
        // select d-th set bit: clear d lowest set bits, then ctz (predicated, no branches)
        if (d > 0u) f &= f - 1u;
        if (d > 1u) f &= f - 1u;
        if (d > 2u) f &= f - 1u;
        Xp = (Xp << 3) | (unsigned)__builtin_ctz(f);
    }
    unsigned f9 = (unsigned)flags[87381u + q];

    const float s0 = scl3[0], s1 = scl3[1], s2 = scl3[2];
    const float o0 = off3[0], o1 = off3[1], o2 = off3[2];

    float4 v[3];
    float* vf = (float*)v;
    const unsigned base = Xp << 3;
    unsigned f = f9;
#pragma unroll
    for (int d = 0; d < 4; ++d) {
        const unsigned j = (unsigned)__builtin_ctz(f);  // set bits ascending = child order
        f &= f - 1u;
        const unsigned X  = base | j;
        const unsigned Xr = __brev(X) >> 2;             // 30-bit reversal
        vf[3 * d + 0] = fmaf((float)(Xr & 1023u),         s0, o0);
        vf[3 * d + 1] = fmaf((float)((Xr >> 10) & 1023u), s1, o1);
        vf[3 * d + 2] = fmaf((float)((Xr >> 20) & 1023u), s2, o2);
    }

    // 12 floats = 48 B per thread, 16B-aligned (48*q), coalesced float4 stores
    float4* outv = (float4*)(out + 12u * (size_t)q);
    outv[0] = v[0];
    outv[1] = v[1];
    outv[2] = v[2];
}

extern "C" void kernel_launch(void* const* d_in, const int* in_sizes, int n_in,
                              void* d_out, int out_size, void* d_ws, size_t ws_size,
                              hipStream_t stream) {
    const int*   flags  = (const int*)d_in[0];
    const float* offset = (const float*)d_in[1];
    const float* scale  = (const float*)d_in[2];
    float*       out    = (float*)d_out;

    // 2^18 level-9 nodes, 256 threads/block -> 1024 blocks
    nbit_tree_decode<<<dim3(1024), dim3(256), 0, stream>>>(flags, offset, scale, out);
}

// Round 2
// 63.716 us; speedup vs baseline: 1.0155x; 1.0155x over previous
//
#include <hip/hip_runtime.h>

// NbitTreeDecoder: static-shape tree decode (K=4 children, 8-bit flags, depth 10).
// One thread per level-9 node (2^18 threads), 4 leaves per thread.
// Levels 0..5 have wave-uniform node index AND digit -> scalar pipe via readfirstlane.
// Output staged through XOR-swizzled LDS so global stores are perfectly contiguous.

__device__ __forceinline__ unsigned sel_bit(unsigned f, unsigned d) {
    // position of d-th set bit of f (d in 0..3)
    if (d > 0u) f &= f - 1u;
    if (d > 1u) f &= f - 1u;
    if (d > 2u) f &= f - 1u;
    return (unsigned)__builtin_ctz(f);
}

__device__ __forceinline__ unsigned swz(unsigned s) {  // float4-slot swizzle, bijective per 8-block
    return s ^ ((s >> 3) & 7u);
}

__global__ __launch_bounds__(256) void nbit_tree_decode(
    const int* __restrict__ flags,
    const float* __restrict__ off3,
    const float* __restrict__ scl3,
    float* __restrict__ out)
{
    // level offsets (4^t - 1) / 3 for t = 0..9
    constexpr unsigned LOFF[10] = {0u, 1u, 5u, 21u, 85u, 341u, 1365u, 5461u, 21845u, 87381u};

    const unsigned tid = threadIdx.x;
    const unsigned q = blockIdx.x * 256u + tid;   // level-9 node index, < 2^18

    // ---- levels 0..5: wave-uniform (q>>6 identical across the 64-lane wave) ----
    // Force onto the scalar pipe: scalar loads + s_ff1 selection.
    const unsigned qw = __builtin_amdgcn_readfirstlane(q);
    unsigned Xs = 0u;  // 18-bit scalar prefix
#pragma unroll
    for (int t = 0; t < 6; ++t) {
        const unsigned i = qw >> (18 - 2 * t);
        const unsigned d = (qw >> (16 - 2 * t)) & 3u;
        const unsigned f = (unsigned)flags[LOFF[t] + i];
        Xs = (Xs << 3) | sel_bit(f, d);
    }

    // ---- levels 6..8: per-lane ----
    unsigned Xv = 0u;
#pragma unroll
    for (int t = 6; t < 9; ++t) {
        const unsigned i = q >> (18 - 2 * t);
        const unsigned d = (q >> (16 - 2 * t)) & 3u;
        const unsigned f = (unsigned)flags[LOFF[t] + i];
        Xv = (Xv << 3) | sel_bit(f, d);
    }
    const unsigned base = ((Xs << 9) | Xv) << 3;   // 27-bit prefix, shifted for leaf digit

    const unsigned f9 = (unsigned)flags[LOFF[9] + q];

    const float s0 = scl3[0], s1 = scl3[1], s2 = scl3[2];
    const float o0 = off3[0], o1 = off3[1], o2 = off3[2];

    float4 v[3];
    float* vf = (float*)v;
    unsigned f = f9;
#pragma unroll
    for (int d = 0; d < 4; ++d) {
        const unsigned j = (unsigned)__builtin_ctz(f);  // set bits ascending = child order
        f &= f - 1u;
        const unsigned X  = base | j;
        const unsigned Xr = __brev(X) >> 2;             // 30-bit reversal (PERMUTE)
        vf[3 * d + 0] = fmaf((float)(Xr & 1023u),         s0, o0);
        vf[3 * d + 1] = fmaf((float)((Xr >> 10) & 1023u), s1, o1);
        vf[3 * d + 2] = fmaf((float)((Xr >> 20) & 1023u), s2, o2);
    }

    // ---- LDS stage: block image is 768 float4 (3072 floats); XOR swizzle kills
    // the stride-3 write conflicts; read side is a per-8-group permutation. ----
    __shared__ float4 stage[768];
#pragma unroll
    for (int k = 0; k < 3; ++k)
        stage[swz(3u * tid + k)] = v[k];
    __syncthreads();

    float4* og = (float4*)out + (size_t)blockIdx.x * 768u;
#pragma unroll
    for (int k = 0; k < 3; ++k) {
        const unsigned s = 256u * k + tid;
        og[s] = stage[swz(s)];   // lanes write contiguous 1024B per instruction
    }
}

extern "C" void kernel_launch(void* const* d_in, const int* in_sizes, int n_in,
                              void* d_out, int out_size, void* d_ws, size_t ws_size,
                              hipStream_t stream) {
    const int*   flags  = (const int*)d_in[0];
    const float* offset = (const float*)d_in[1];
    const float* scale  = (const float*)d_in[2];
    float*       out    = (float*)d_out;

    nbit_tree_decode<<<dim3(1024), dim3(256), 0, stream>>>(flags, offset, scale, out);
}